// Round 4
// baseline (348.909 us; speedup 1.0000x reference)
//
#include <hip/hip_runtime.h>

namespace {
constexpr int kB      = 8;
constexpr int kN      = 1024;
constexpr int kM      = 24;          // FIR taps j = 1..24
constexpr int kP      = 80;          // frame period
constexpr int kT      = kN * kP;     // 81920
constexpr int kTaylor = 20;
constexpr int kTB     = 1280;        // time tile per block
constexpr int kBlkT   = kT / kTB;    // 64 tiles per batch
constexpr int kHalo   = kTaylor * kM;    // 480
constexpr int kE      = kTB + kHalo;     // 1760 extended samples
constexpr int kChunks = kE / 4;          // 440 4-sample chunks
constexpr int kThreads = 448;            // 7 waves
constexpr int kFrames  = 22;             // staged coefficient frames
constexpr int kReps    = 4;              // probe amplification
}

// ---------------- ceff body (round-3 structure), REPS-amplified ----------------
template <int REPS>
__device__ __forceinline__ void run_ceff(const float* __restrict__ x,
                                         const float* __restrict__ mc,
                                         const float* __restrict__ av,
                                         const float* __restrict__ wv,
                                         float* __restrict__ outp) {
  __shared__ float sbuf[2][kE];
  __shared__ float scb[kFrames][kM + 1];
  __shared__ float scd[kFrames][kM + 1];
  __shared__ float s_a[kTaylor + 1];
  __shared__ float s_w[kTaylor + 1];

  const int tid = (int)threadIdx.x;
  const int blk = (int)blockIdx.x;
  const int b   = blk / kBlkT;
  const int t0  = (blk % kBlkT) * kTB;
  const int fbase = t0 / kP - kHalo / kP;

  if (tid <= kTaylor) { s_a[tid] = av[tid]; s_w[tid] = wv[tid]; }

  const float* mcb = mc + (size_t)b * kN * (kM + 1);
  for (int s = tid; s < kFrames * (kM + 1); s += kThreads) {
    const int lf = s / (kM + 1);
    const int j  = s - lf * (kM + 1);
    const int f  = fbase + lf;
    const int f0 = f < 0 ? 0 : (f > kN - 1 ? kN - 1 : f);
    const int f1 = (f + 1) < 0 ? 0 : ((f + 1) > kN - 1 ? kN - 1 : f + 1);
    const float vb = mcb[f0 * (kM + 1) + j];
    const float vn = mcb[f1 * (kM + 1) + j];
    scb[lf][j] = vb;
    scd[lf][j] = vn - vb;
  }
  __syncthreads();

  const int  c      = tid;
  const bool valid  = c < kChunks;
  const int  e0     = 4 * c;
  const int  tg     = t0 - kHalo + e0;
  const bool act    = valid && (tg >= 0);
  const bool is_out = valid && (c >= kHalo / 4);

  float ceff[4][kM];
  float wfr[4] = {0.f, 0.f, 0.f, 0.f};
  float cb0 = 0.f, cd0 = 0.f;
  if (act) {
    const int lf = c / 20;
    const int ph = (4 * c) % kP;
#pragma unroll
    for (int q = 0; q < 4; ++q) wfr[q] = (float)(ph + q) * (1.0f / kP);
    cb0 = scb[lf][0];
    cd0 = scd[lf][0];
#pragma unroll
    for (int j = 1; j <= kM; ++j) {
      const float vb = scb[lf][j];
      const float vd = scd[lf][j];
#pragma unroll
      for (int q = 0; q < 4; ++q) ceff[q][j - 1] = fmaf(wfr[q], vd, vb);
    }
  }

  float yaccT[4] = {0.f, 0.f, 0.f, 0.f};

#pragma unroll 1
  for (int rep = 0; rep < REPS; ++rep) {
    __syncthreads();                       // protect prev-rep reads before re-init
    float cur[4] = {0.f, 0.f, 0.f, 0.f};
    if (act) {
      const float4 v = *reinterpret_cast<const float4*>(x + (size_t)b * kT + tg);
      cur[0] = v.x; cur[1] = v.y; cur[2] = v.z; cur[3] = v.w;
    }
    if (valid) {
      float4 v;
      v.x = cur[0]; v.y = cur[1]; v.z = cur[2]; v.w = cur[3];
      *reinterpret_cast<float4*>(&sbuf[0][e0]) = v;
      if (tg < 0) *reinterpret_cast<float4*>(&sbuf[1][e0]) = make_float4(0.f, 0.f, 0.f, 0.f);
    }

    float yacc[4] = {0.f, 0.f, 0.f, 0.f};
    if (is_out) {
      const float a0 = s_a[0];
#pragma unroll
      for (int q = 0; q < 4; ++q) yacc[q] = a0 * cur[q];
    }

#pragma unroll 1
    for (int i = 1; i <= kTaylor; ++i) {
      const int pb   = (i - 1) & 1;
      const int cbuf = i & 1;
      const float wi = s_w[i];
      const float ai = s_a[i];
      __syncthreads();
      if (act && c >= 6 * i) {
        float win[28];
#pragma unroll
        for (int s = 0; s < 6; ++s) {
          const float4 v = *reinterpret_cast<const float4*>(&sbuf[pb][e0 - kM + 4 * s]);
          win[4 * s + 0] = v.x; win[4 * s + 1] = v.y;
          win[4 * s + 2] = v.z; win[4 * s + 3] = v.w;
        }
#pragma unroll
        for (int q = 0; q < 4; ++q) win[24 + q] = cur[q];
        float acc[4] = {0.f, 0.f, 0.f, 0.f};
#pragma unroll
        for (int j = 1; j <= kM; ++j) {
#pragma unroll
          for (int q = 0; q < 4; ++q)
            acc[q] = fmaf(win[kM + q - j], ceff[q][j - 1], acc[q]);
        }
#pragma unroll
        for (int q = 0; q < 4; ++q) cur[q] = acc[q] * wi;
        float4 cv;
        cv.x = cur[0]; cv.y = cur[1]; cv.z = cur[2]; cv.w = cur[3];
        *reinterpret_cast<float4*>(&sbuf[cbuf][e0]) = cv;
#pragma unroll
        for (int q = 0; q < 4; ++q) yacc[q] += ai * cur[q];
      }
    }
#pragma unroll
    for (int q = 0; q < 4; ++q) yaccT[q] += yacc[q];
  }

  if (is_out) {
    float4 o;
    o.x = yaccT[0] * __expf(cb0 + wfr[0] * cd0);
    o.y = yaccT[1] * __expf(cb0 + wfr[1] * cd0);
    o.z = yaccT[2] * __expf(cb0 + wfr[2] * cd0);
    o.w = yaccT[3] * __expf(cb0 + wfr[3] * cd0);
    *reinterpret_cast<float4*>(outp + (size_t)b * kT + tg) = o;
  }
}

// ---------------- dual-accumulator body (48 coeff regs), REPS-amplified ----------------
template <int REPS>
__device__ __forceinline__ void run_dual(const float* __restrict__ x,
                                         const float* __restrict__ mc,
                                         const float* __restrict__ av,
                                         const float* __restrict__ wv,
                                         float* __restrict__ outp) {
  __shared__ float sbuf[2][kE];
  __shared__ float scb[kFrames][kM + 1];
  __shared__ float scd[kFrames][kM + 1];
  __shared__ float s_a[kTaylor + 1];
  __shared__ float s_w[kTaylor + 1];

  const int tid = (int)threadIdx.x;
  const int blk = (int)blockIdx.x;
  const int b   = blk / kBlkT;
  const int t0  = (blk % kBlkT) * kTB;
  const int fbase = t0 / kP - kHalo / kP;

  if (tid <= kTaylor) { s_a[tid] = av[tid]; s_w[tid] = wv[tid]; }

  const float* mcb = mc + (size_t)b * kN * (kM + 1);
  for (int s = tid; s < kFrames * (kM + 1); s += kThreads) {
    const int lf = s / (kM + 1);
    const int j  = s - lf * (kM + 1);
    const int f  = fbase + lf;
    const int f0 = f < 0 ? 0 : (f > kN - 1 ? kN - 1 : f);
    const int f1 = (f + 1) < 0 ? 0 : ((f + 1) > kN - 1 ? kN - 1 : f + 1);
    const float vb = mcb[f0 * (kM + 1) + j];
    const float vn = mcb[f1 * (kM + 1) + j];
    scb[lf][j] = vb;
    scd[lf][j] = vn - vb;
  }
  __syncthreads();

  const int  c      = tid;
  const bool valid  = c < kChunks;
  const int  e0     = 4 * c;
  const int  tg     = t0 - kHalo + e0;
  const bool act    = valid && (tg >= 0);
  const bool is_out = valid && (c >= kHalo / 4);

  float cb[kM], cd[kM];
  float wfr[4] = {0.f, 0.f, 0.f, 0.f};
  float cb0 = 0.f, cd0 = 0.f;
  if (act) {
    const int lf = c / 20;
    const int ph = (4 * c) % kP;
#pragma unroll
    for (int q = 0; q < 4; ++q) wfr[q] = (float)(ph + q) * (1.0f / kP);
    cb0 = scb[lf][0];
    cd0 = scd[lf][0];
#pragma unroll
    for (int j = 1; j <= kM; ++j) { cb[j - 1] = scb[lf][j]; cd[j - 1] = scd[lf][j]; }
  }

  float yaccT[4] = {0.f, 0.f, 0.f, 0.f};

#pragma unroll 1
  for (int rep = 0; rep < REPS; ++rep) {
    __syncthreads();
    float cur[4] = {0.f, 0.f, 0.f, 0.f};
    if (act) {
      const float4 v = *reinterpret_cast<const float4*>(x + (size_t)b * kT + tg);
      cur[0] = v.x; cur[1] = v.y; cur[2] = v.z; cur[3] = v.w;
    }
    if (valid) {
      float4 v;
      v.x = cur[0]; v.y = cur[1]; v.z = cur[2]; v.w = cur[3];
      *reinterpret_cast<float4*>(&sbuf[0][e0]) = v;
      if (tg < 0) *reinterpret_cast<float4*>(&sbuf[1][e0]) = make_float4(0.f, 0.f, 0.f, 0.f);
    }

    float yacc[4] = {0.f, 0.f, 0.f, 0.f};
    if (is_out) {
      const float a0 = s_a[0];
#pragma unroll
      for (int q = 0; q < 4; ++q) yacc[q] = a0 * cur[q];
    }

#pragma unroll 1
    for (int i = 1; i <= kTaylor; ++i) {
      const int pb   = (i - 1) & 1;
      const int cbuf = i & 1;
      const float wi = s_w[i];
      const float ai = s_a[i];
      __syncthreads();
      if (act && c >= 6 * i) {
        float win[28];
#pragma unroll
        for (int s = 0; s < 6; ++s) {
          const float4 v = *reinterpret_cast<const float4*>(&sbuf[pb][e0 - kM + 4 * s]);
          win[4 * s + 0] = v.x; win[4 * s + 1] = v.y;
          win[4 * s + 2] = v.z; win[4 * s + 3] = v.w;
        }
#pragma unroll
        for (int q = 0; q < 4; ++q) win[24 + q] = cur[q];
        float accb[4] = {0.f, 0.f, 0.f, 0.f};
        float accd[4] = {0.f, 0.f, 0.f, 0.f};
#pragma unroll
        for (int j = 1; j <= kM; ++j) {
#pragma unroll
          for (int q = 0; q < 4; ++q) {
            const float v = win[kM + q - j];
            accb[q] = fmaf(v, cb[j - 1], accb[q]);
            accd[q] = fmaf(v, cd[j - 1], accd[q]);
          }
        }
#pragma unroll
        for (int q = 0; q < 4; ++q)
          cur[q] = (accb[q] + wfr[q] * accd[q]) * wi;
        float4 cv;
        cv.x = cur[0]; cv.y = cur[1]; cv.z = cur[2]; cv.w = cur[3];
        *reinterpret_cast<float4*>(&sbuf[cbuf][e0]) = cv;
#pragma unroll
        for (int q = 0; q < 4; ++q) yacc[q] += ai * cur[q];
      }
    }
#pragma unroll
    for (int q = 0; q < 4; ++q) yaccT[q] += yacc[q];
  }

  if (is_out) {
    float4 o;
    o.x = yaccT[0] * __expf(cb0 + wfr[0] * cd0);
    o.y = yaccT[1] * __expf(cb0 + wfr[1] * cd0);
    o.z = yaccT[2] * __expf(cb0 + wfr[2] * cd0);
    o.w = yaccT[3] * __expf(cb0 + wfr[3] * cd0);
    *reinterpret_cast<float4*>(outp + (size_t)b * kT + tg) = o;
  }
}

// A: real output, exact round-3 config (bounds 4 -> 128 VGPR cap)
__global__ __launch_bounds__(kThreads, 4)
void mlsaA_real(const float* __restrict__ x, const float* __restrict__ mc,
                const float* __restrict__ av, const float* __restrict__ wv,
                float* __restrict__ out) {
  run_ceff<1>(x, mc, av, wv, out);
}

// B probe: same body/bounds as A, x4 reps -> top-5 visible counters
__global__ __launch_bounds__(kThreads, 4)
void mlsaB_ceff_b4(const float* __restrict__ x, const float* __restrict__ mc,
                   const float* __restrict__ av, const float* __restrict__ wv,
                   float* __restrict__ ws) {
  run_ceff<kReps>(x, mc, av, wv, ws);
}

// C probe: same body, bounds 3 (170 VGPR cap, no register squeeze), x4 reps
__global__ __launch_bounds__(kThreads, 3)
void mlsaC_ceff_b3(const float* __restrict__ x, const float* __restrict__ mc,
                   const float* __restrict__ av, const float* __restrict__ wv,
                   float* __restrict__ ws) {
  run_ceff<kReps>(x, mc, av, wv, ws);
}

// D probe: dual-acc body (~116 VGPR, honestly fits bounds-4 cap), x4 reps
__global__ __launch_bounds__(kThreads, 4)
void mlsaD_dual_b4(const float* __restrict__ x, const float* __restrict__ mc,
                   const float* __restrict__ av, const float* __restrict__ wv,
                   float* __restrict__ ws) {
  run_dual<kReps>(x, mc, av, wv, ws);
}

extern "C" void kernel_launch(void* const* d_in, const int* in_sizes, int n_in,
                              void* d_out, int out_size, void* d_ws, size_t ws_size,
                              hipStream_t stream) {
  const float* x  = (const float*)d_in[0];
  const float* mc = (const float*)d_in[1];
  const float* a  = (const float*)d_in[2];
  const float* w  = (const float*)d_in[3];
  float* out = (float*)d_out;
  float* ws  = (float*)d_ws;
  dim3 grid(kB * kBlkT);
  dim3 block(kThreads);
  hipLaunchKernelGGL(mlsaA_real,    grid, block, 0, stream, x, mc, a, w, out);
  hipLaunchKernelGGL(mlsaB_ceff_b4, grid, block, 0, stream, x, mc, a, w, ws);
  hipLaunchKernelGGL(mlsaC_ceff_b3, grid, block, 0, stream, x, mc, a, w, ws + (size_t)kB * kT);
  hipLaunchKernelGGL(mlsaD_dual_b4, grid, block, 0, stream, x, mc, a, w, ws + 2 * (size_t)kB * kT);
}